// Round 2
// baseline (224.706 us; speedup 1.0000x reference)
//
#include <hip/hip_runtime.h>

// ---------------------------------------------------------------------------
// DoReFa BasicBlock on MI355X: both 3x3 convs as exact int8 implicit GEMM,
// now with the 256x256 / 8-wave / 8-phase counted-vmcnt schedule (T2-T5).
//   acts   quantized to a_int in {0..3}       (value = a_int/3)
//   weights quantized to w_int in {-3,-1,1,3} (value = w_int/3)
//   conv_f32 = (sum a_int*w_int) / 9  -> folded into BN scale s = inv/9.
// Workspace: [0,1024) mx; s1/t1/s2/t2 @1024..5120; a1,a2 padded NHWC u8
// [64][30][30][256]; wq1,wq2 i8 [256][9*256]. Borders of a1/a2 zeroed by
// border_zero (3.8 MB) instead of a 29.5 MB memset.
// ---------------------------------------------------------------------------

#define ABUF 14745600
using i32x4 = __attribute__((ext_vector_type(4))) int;

__device__ __forceinline__ void gload16(const void* g, void* l) {
  typedef const __attribute__((address_space(1))) unsigned int* gp_t;
  typedef __attribute__((address_space(3))) unsigned int* lp_t;
  __builtin_amdgcn_global_load_lds((gp_t)g, (lp_t)l, 16, 0, 0);
}

// ---- BN constant prep ------------------------------------------------------
__global__ void prep_bn(const float* g1, const float* b1, const float* m1, const float* v1,
                        const float* g2, const float* b2, const float* m2, const float* v2,
                        float* s1, float* t1, float* s2, float* t2) {
  int c = threadIdx.x;
  float i1 = g1[c] / sqrtf(v1[c] + 1e-5f);
  s1[c] = i1 * (1.f / 9.f);
  t1[c] = b1[c] - m1[c] * i1;
  float i2 = g2[c] / sqrtf(v2[c] + 1e-5f);
  s2[c] = i2 * (1.f / 9.f);
  t2[c] = b2[c] - m2[c] * i2;
}

// ---- max|w| ----------------------------------------------------------------
__global__ void maxabs_k(const float* __restrict__ w1, const float* __restrict__ w2,
                         unsigned* mx) {
  const float4* v = (const float4*)(blockIdx.y ? w2 : w1);
  float loc = 0.f;
  for (int i = blockIdx.x * 256 + threadIdx.x; i < 147456; i += 65536) {
    float4 f = v[i];
    loc = fmaxf(loc, fmaxf(fmaxf(fabsf(f.x), fabsf(f.y)), fmaxf(fabsf(f.z), fabsf(f.w))));
  }
  #pragma unroll
  for (int off = 32; off; off >>= 1) loc = fmaxf(loc, __shfl_xor(loc, off));
  __shared__ float red[4];
  if ((threadIdx.x & 63) == 0) red[threadIdx.x >> 6] = loc;
  __syncthreads();
  if (threadIdx.x == 0) {
    loc = fmaxf(fmaxf(red[0], red[1]), fmaxf(red[2], red[3]));
    atomicMax(&mx[blockIdx.y], __float_as_uint(loc));
  }
}

// ---- weight quantize: OIHW f32 -> [O][tap][I] i8 ---------------------------
__global__ void wquant_k(const float* __restrict__ w1, const float* __restrict__ w2,
                         const unsigned* __restrict__ mx,
                         signed char* __restrict__ wq1, signed char* __restrict__ wq2) {
  const float* w = blockIdx.y ? w2 : w1;
  signed char* o = blockIdx.y ? wq2 : wq1;
  int idx = blockIdx.x * 256 + threadIdx.x;
  int oo = idx / 2304, rr = idx % 2304, t9 = rr >> 8, ci = rr & 255;
  float mt = tanhf(__uint_as_float(mx[blockIdx.y]));
  float t = tanhf(w[oo * 2304 + ci * 9 + t9]) / (2.f * mt) + 0.5f;
  int q = (int)rintf(t * 3.f);
  o[idx] = (signed char)(2 * q - 3);
}

// ---- zero only the padded borders of a1/a2 (~3.8 MB vs 29.5 MB memset) -----
__global__ void border_zero(unsigned char* __restrict__ a1, unsigned char* __restrict__ a2) {
  int b = blockIdx.x;                 // 128 blocks: [buf][n]
  unsigned char* base = (b >= 64 ? a2 : a1) + (size_t)(b & 63) * 230400;
  int tid = threadIdx.x;
  #pragma unroll
  for (int it = 0; it < 8; ++it) {
    int pi = it * 16 + (tid >> 4);
    if (pi < 116) {
      int hh, ww;
      if (pi < 30)      { hh = 0;       ww = pi; }
      else if (pi < 60) { hh = 29;      ww = pi - 30; }
      else if (pi < 88) { hh = pi - 59; ww = 0; }
      else              { hh = pi - 87; ww = 29; }
      *(uint4*)(base + (hh * 30 + ww) * 256 + (tid & 15) * 16) = uint4{0, 0, 0, 0};
    }
  }
}

// ---- act quantize + NCHW -> padded NHWC i8 ---------------------------------
__global__ void aquant_k(const float* __restrict__ x, unsigned char* __restrict__ a1) {
  int n = blockIdx.x / 28, h = blockIdx.x % 28;
  __shared__ __align__(16) unsigned char l[28 * 256];
  int c = threadIdx.x;
  const float4* src = (const float4*)(x + (size_t)(n * 256 + c) * 784 + h * 28);
  #pragma unroll
  for (int i = 0; i < 7; ++i) {
    float4 f = src[i];
    int p = i * 4;
    l[(p + 0) * 256 + c] = (unsigned char)(int)rintf(3.f * fminf(fmaxf(f.x, 0.f), 1.f));
    l[(p + 1) * 256 + c] = (unsigned char)(int)rintf(3.f * fminf(fmaxf(f.y, 0.f), 1.f));
    l[(p + 2) * 256 + c] = (unsigned char)(int)rintf(3.f * fminf(fmaxf(f.z, 0.f), 1.f));
    l[(p + 3) * 256 + c] = (unsigned char)(int)rintf(3.f * fminf(fmaxf(f.w, 0.f), 1.f));
  }
  __syncthreads();
  if (threadIdx.x < 224) {
    int p = threadIdx.x >> 3, q = threadIdx.x & 7;
    const uint4* s = (const uint4*)&l[p * 256 + q * 32];
    uint4 v0 = s[0], v1 = s[1];
    unsigned char* dst = a1 + ((size_t)((n * 30 + h + 1) * 30) + (p + 1)) * 256 + q * 32;
    ((uint4*)dst)[0] = v0;
    ((uint4*)dst)[1] = v1;
  }
}

// ---------------------------------------------------------------------------
// conv as implicit GEMM, 8-phase schedule.
// Tile: 256 pixels x 256 channels, BK=128 bytes, 18 K-tiles, 9 iterations x
// 2 tiles. 8 waves: wvm in {0,1} (A-operand rows, 2x128), wvn 0..3 (B cols,
// 4x64). LDS: [buf 2][pix 32K | w 32K] = 128 KiB dynamic; XOR (row&7) slot
// swizzle on reads, inverse-swizzled global sources (linear gload_lds dest).
// Stage ledger (A=MFMA A-operand tile, B=B-operand; both halves of a tile are
// read in ph1-ph3 of its 4-phase group): ph1: Y.A1 | ph3: X'.B0 | ph4: X'.A0
// + X'.B1 | ph5: X'.A1 | ph7: Y'.B0 | ph8: Y'.A0 + Y'.B1. vmcnt(6) at ph4 &
// ph8 => current tile fully landed, 3 halves in flight. Last iter: vmcnt(0)
// at ph4. MODE 0: mfma(pix,w), epilogue BN1+ReLU+requant via LDS transpose ->
// coalesced u8. MODE 1: mfma(w,pix), epilogue BN2+residual+ReLU -> f32 NCHW.
// ---------------------------------------------------------------------------
#define PH_MID() do { __builtin_amdgcn_s_barrier(); \
  asm volatile("s_waitcnt lgkmcnt(0)" ::: "memory"); \
  __builtin_amdgcn_sched_barrier(0); \
  __builtin_amdgcn_s_setprio(1); } while (0)
#define PH_END() do { __builtin_amdgcn_s_setprio(0); \
  __builtin_amdgcn_s_barrier(); } while (0)
#define PH_ENDV(N) do { __builtin_amdgcn_s_setprio(0); \
  asm volatile("s_waitcnt vmcnt(" #N ")" ::: "memory"); \
  __builtin_amdgcn_sched_barrier(0); \
  __builtin_amdgcn_s_barrier(); } while (0)

template <int MODE>
__global__ __launch_bounds__(512, 2) void conv_gemm(
    const unsigned char* __restrict__ act, const signed char* __restrict__ wq,
    const float* __restrict__ sC, const float* __restrict__ tC,
    const float* __restrict__ xres, unsigned char* __restrict__ actout,
    float* __restrict__ fout) {
  extern __shared__ __align__(16) char lds[];
  const int tid = threadIdx.x, wv = tid >> 6, lane = tid & 63;
  const int pixBase = blockIdx.x * 256;
  const int wvm = wv >> 2, wvn = wv & 3;
  constexpr int RAoff = (MODE == 0) ? 0 : 32768;   // A-operand region
  constexpr int RBoff = 32768 - RAoff;

  // staging source bases: row r = h*128 + c*64 + wv*8 + (lane>>3); the
  // source 16B-slot is inverse-swizzled so linear LDS + XOR read works.
  int pixB[2][2], wB[2][2];
  {
    int s = (lane & 7) ^ ((lane >> 3) & 7);
    #pragma unroll
    for (int h = 0; h < 2; ++h)
      #pragma unroll
      for (int c = 0; c < 2; ++c) {
        int r = h * 128 + c * 64 + wv * 8 + (lane >> 3);
        int p = pixBase + r;
        int n = p / 784, rem = p % 784, hh = rem / 28, ww = rem % 28;
        pixB[h][c] = (((n * 30 + hh) * 30 + ww) << 8) + (s << 4);
        wB[h][c] = r * 2304 + (s << 4);
      }
  }
  auto tof = [](int kt) {
    int tap = kt >> 1;
    return ((tap / 3) * 30 + (tap % 3)) * 256 + ((kt & 1) << 7);
  };
  auto stagePix = [&](int h, int kt) {
    const int base = (kt & 1) * 65536 + h * 16384 + wv * 1024;
    const int toff = tof(kt);
    gload16(act + pixB[h][0] + toff, &lds[base]);
    gload16(act + pixB[h][1] + toff, &lds[base + 8192]);
  };
  auto stageW = [&](int h, int kt) {
    const int base = (kt & 1) * 65536 + 32768 + h * 16384 + wv * 1024;
    gload16(wq + wB[h][0] + kt * 128, &lds[base]);
    gload16(wq + wB[h][1] + kt * 128, &lds[base + 8192]);
  };
  auto stageA = [&](int h, int kt) { if (MODE == 0) stagePix(h, kt); else stageW(h, kt); };
  auto stageB = [&](int h, int kt) { if (MODE == 0) stageW(h, kt); else stagePix(h, kt); };

  i32x4 acc[8][4];
  #pragma unroll
  for (int i = 0; i < 8; ++i)
    #pragma unroll
    for (int j = 0; j < 4; ++j) acc[i][j] = (i32x4){0, 0, 0, 0};
  i32x4 pa[4][2], pb0[2][2], pb1[2][2];

  auto rdA = [&](int buf, int mh) {
    #pragma unroll
    for (int f = 0; f < 4; ++f) {
      int r = wvm * 128 + mh * 64 + f * 16 + (lane & 15);
      int rb = buf * 65536 + RAoff + r * 128;
      #pragma unroll
      for (int kc = 0; kc < 2; ++kc) {
        int sl = kc * 4 + (lane >> 4);
        pa[f][kc] = *(const i32x4*)&lds[rb + ((sl ^ (r & 7)) << 4)];
      }
    }
  };
  auto rdB = [&](int buf, int nh, i32x4 (*pb)[2]) {
    #pragma unroll
    for (int g = 0; g < 2; ++g) {
      int r = wvn * 64 + nh * 32 + g * 16 + (lane & 15);
      int rb = buf * 65536 + RBoff + r * 128;
      #pragma unroll
      for (int kc = 0; kc < 2; ++kc) {
        int sl = kc * 4 + (lane >> 4);
        pb[g][kc] = *(const i32x4*)&lds[rb + ((sl ^ (r & 7)) << 4)];
      }
    }
  };
  auto quad = [&](int mh, int nh, i32x4 (*pb)[2]) {
    #pragma unroll
    for (int f = 0; f < 4; ++f)
      #pragma unroll
      for (int g = 0; g < 2; ++g)
        #pragma unroll
        for (int kc = 0; kc < 2; ++kc)
          acc[mh * 4 + f][nh * 2 + g] = __builtin_amdgcn_mfma_i32_16x16x64_i8(
              pa[f][kc], pb[g][kc], acc[mh * 4 + f][nh * 2 + g], 0, 0, 0);
  };

  // prologue: tile0 (B0,A0,B1,A1) + tile1 (B0,A0,B1); wait tile0; barrier.
  stageB(0, 0); stageA(0, 0); stageB(1, 0); stageA(1, 0);
  stageB(0, 1); stageA(0, 1); stageB(1, 1);
  asm volatile("s_waitcnt vmcnt(6)" ::: "memory");
  __builtin_amdgcn_sched_barrier(0);
  __builtin_amdgcn_s_barrier();

  for (int it = 0; it < 9; ++it) {
    const int ktY = 2 * it + 1, ktX2 = 2 * it + 2, ktY2 = 2 * it + 3;
    const bool st = (it < 8);
    // ph1: quad(0,0) on buf0
    rdA(0, 0); rdB(0, 0, pb0);
    stageA(1, ktY);
    PH_MID(); quad(0, 0, pb0); PH_END();
    // ph2: quad(0,1)
    rdB(0, 1, pb1);
    PH_MID(); quad(0, 1, pb1); PH_END();
    // ph3: quad(1,0)
    rdA(0, 1);
    if (st) stageB(0, ktX2);
    PH_MID(); quad(1, 0, pb0); PH_END();
    // ph4: quad(1,1)
    if (st) { stageA(0, ktX2); stageB(1, ktX2); }
    PH_MID(); quad(1, 1, pb1);
    if (st) { PH_ENDV(6); } else { PH_ENDV(0); }
    // ph5: quad(0,0) on buf1
    rdA(1, 0); rdB(1, 0, pb0);
    if (st) stageA(1, ktX2);
    PH_MID(); quad(0, 0, pb0); PH_END();
    // ph6
    rdB(1, 1, pb1);
    PH_MID(); quad(0, 1, pb1); PH_END();
    // ph7
    rdA(1, 1);
    if (st) stageB(0, ktY2);
    PH_MID(); quad(1, 0, pb0); PH_END();
    // ph8
    if (st) { stageA(0, ktY2); stageB(1, ktY2); }
    PH_MID(); quad(1, 1, pb1);
    PH_ENDV(6);
  }

  if (MODE == 0) {
    // BN1 + ReLU + 2-bit requant; LDS transpose [pix 256][ch 256] (XOR'd) so
    // global writes are coalesced 16B.
    float sj[4], tj[4];
    #pragma unroll
    for (int j = 0; j < 4; ++j) {
      int c = wvn * 64 + j * 16 + (lane & 15);
      sj[j] = sC[c]; tj[j] = tC[c];
    }
    __syncthreads();
    #pragma unroll
    for (int i = 0; i < 8; ++i) {
      int lp0 = wvm * 128 + i * 16 + ((lane >> 4) << 2);
      #pragma unroll
      for (int j = 0; j < 4; ++j) {
        int lch = wvn * 64 + j * 16 + (lane & 15);
        #pragma unroll
        for (int r = 0; r < 4; ++r) {
          float y = (float)acc[i][j][r] * sj[j] + tj[j];
          y = fminf(fmaxf(y, 0.f), 1.f);
          int lp = lp0 + r;
          lds[lp * 256 + (lch ^ ((lp & 7) << 4))] = (char)(int)rintf(y * 3.f);
        }
      }
    }
    __syncthreads();
    int rr = tid >> 1, hf = tid & 1;
    int p = pixBase + rr;
    int n = p / 784, rem = p % 784, hh = rem / 28, ww = rem % 28;
    unsigned char* dst = actout + (((n * 30 + hh + 1) * 30 + (ww + 1)) << 8) + hf * 128;
    #pragma unroll
    for (int k = 0; k < 8; ++k) {
      uint4 v = *(const uint4*)&lds[rr * 256 + ((hf * 128 + k * 16) ^ ((rr & 7) << 4))];
      *(uint4*)(dst + k * 16) = v;
    }
  } else {
    // BN2 + residual + ReLU -> f32 NCHW (cols = pixels => coalesced)
    #pragma unroll
    for (int i = 0; i < 8; ++i) {
      #pragma unroll
      for (int r = 0; r < 4; ++r) {
        int c = wvm * 128 + i * 16 + ((lane >> 4) << 2) + r;
        float s = sC[c], t = tC[c];
        #pragma unroll
        for (int j = 0; j < 4; ++j) {
          int m = pixBase + wvn * 64 + j * 16 + (lane & 15);
          int n = m / 784, rem = m % 784;
          int addr = n * 200704 + c * 784 + rem;
          float y = (float)acc[i][j][r] * s + t + xres[addr];
          fout[addr] = fmaxf(y, 0.f);
        }
      }
    }
  }
}

extern "C" void kernel_launch(void* const* d_in, const int* in_sizes, int n_in,
                              void* d_out, int out_size, void* d_ws, size_t ws_size,
                              hipStream_t stream) {
  const float* x  = (const float*)d_in[0];
  const float* w1 = (const float*)d_in[1];
  const float* g1 = (const float*)d_in[2];
  const float* b1 = (const float*)d_in[3];
  const float* m1 = (const float*)d_in[4];
  const float* v1 = (const float*)d_in[5];
  const float* w2 = (const float*)d_in[6];
  const float* g2 = (const float*)d_in[7];
  const float* b2 = (const float*)d_in[8];
  const float* m2 = (const float*)d_in[9];
  const float* v2 = (const float*)d_in[10];

  char* ws = (char*)d_ws;
  unsigned* mx = (unsigned*)ws;
  float* s1 = (float*)(ws + 1024);
  float* t1 = (float*)(ws + 2048);
  float* s2 = (float*)(ws + 3072);
  float* t2 = (float*)(ws + 4096);
  unsigned char* a1 = (unsigned char*)(ws + 8192);
  unsigned char* a2 = a1 + ABUF;
  signed char* wq1 = (signed char*)(a2 + ABUF);
  signed char* wq2 = wq1 + 589824;

  void (*k0)(const unsigned char*, const signed char*, const float*, const float*,
             const float*, unsigned char*, float*) = conv_gemm<0>;
  void (*k1)(const unsigned char*, const signed char*, const float*, const float*,
             const float*, unsigned char*, float*) = conv_gemm<1>;
  hipFuncSetAttribute((const void*)k0, hipFuncAttributeMaxDynamicSharedMemorySize, 131072);
  hipFuncSetAttribute((const void*)k1, hipFuncAttributeMaxDynamicSharedMemorySize, 131072);

  hipMemsetAsync(ws, 0, 1024, stream);
  prep_bn<<<1, 256, 0, stream>>>(g1, b1, m1, v1, g2, b2, m2, v2, s1, t1, s2, t2);
  maxabs_k<<<dim3(256, 2), 256, 0, stream>>>(w1, w2, mx);
  wquant_k<<<dim3(2304, 2), 256, 0, stream>>>(w1, w2, mx, wq1, wq2);
  border_zero<<<128, 256, 0, stream>>>(a1, a2);
  aquant_k<<<64 * 28, 256, 0, stream>>>(x, a1);
  conv_gemm<0><<<196, 512, 131072, stream>>>(a1, wq1, s1, t1, nullptr, a2, nullptr);
  conv_gemm<1><<<196, 512, 131072, stream>>>(a2, wq2, s2, t2, x, nullptr, (float*)d_out);
}

// Round 4
// 221.121 us; speedup vs baseline: 1.0162x; 1.0162x over previous
//
#include <hip/hip_runtime.h>

// ---------------------------------------------------------------------------
// DoReFa BasicBlock on MI355X: both 3x3 convs as exact int8 implicit GEMM,
// 256x256 / 8-wave / 8-phase counted-vmcnt schedule (T2-T5).
//   acts   quantized to a_int in {0..3}       (value = a_int/3)
//   weights quantized to w_int in {-3,-1,1,3} (value = w_int/3)
//   conv_f32 = (sum a_int*w_int) / 9  -> folded into BN scale s = inv/9.
// Round 4: fix maxabs_k loop bound (was scanning 1/4 of the weights ->
// wrong quant scale -> absmax 17). No other changes vs round 3.
// Workspace: [0,512) partial max f32[128]; s1/t1/s2/t2 @1024..5120;
// a1,a2 padded NHWC u8 [64][30][30][256]; wq1,wq2 i8 [256][9*256].
// ---------------------------------------------------------------------------

#define ABUF 14745600
using i32x4 = __attribute__((ext_vector_type(4))) int;

__device__ __forceinline__ void gload16(const void* g, void* l) {
  typedef const __attribute__((address_space(1))) unsigned int* gp_t;
  typedef __attribute__((address_space(3))) unsigned int* lp_t;
  __builtin_amdgcn_global_load_lds((gp_t)g, (lp_t)l, 16, 0, 0);
}

// ---- max|w| partials (64 blocks/tensor) + fused BN prep --------------------
__global__ void maxabs_k(const float* __restrict__ w1, const float* __restrict__ w2,
                         float* __restrict__ partial,
                         const float* g1, const float* b1, const float* m1, const float* v1,
                         const float* g2, const float* b2, const float* m2, const float* v2,
                         float* s1, float* t1, float* s2, float* t2) {
  int t = threadIdx.x, bx = blockIdx.x, ten = blockIdx.y;
  if (ten == 0 && bx == 0) {  // fused prep_bn (c = t)
    float i1 = g1[t] / sqrtf(v1[t] + 1e-5f);
    s1[t] = i1 * (1.f / 9.f);
    t1[t] = b1[t] - m1[t] * i1;
    float i2 = g2[t] / sqrtf(v2[t] + 1e-5f);
    s2[t] = i2 * (1.f / 9.f);
    t2[t] = b2[t] - m2[t] * i2;
  }
  const float4* v = (const float4*)(ten ? w2 : w1);
  float loc = 0.f;
  // 147456 float4 = full 256*256*3*3 f32 tensor; 16384 threads -> 9 iters
  for (int i = bx * 256 + t; i < 147456; i += 16384) {
    float4 f = v[i];
    loc = fmaxf(loc, fmaxf(fmaxf(fabsf(f.x), fabsf(f.y)), fmaxf(fabsf(f.z), fabsf(f.w))));
  }
  #pragma unroll
  for (int off = 32; off; off >>= 1) loc = fmaxf(loc, __shfl_xor(loc, off));
  __shared__ float red[4];
  if ((t & 63) == 0) red[t >> 6] = loc;
  __syncthreads();
  if (t == 0)
    partial[ten * 64 + bx] = fmaxf(fmaxf(red[0], red[1]), fmaxf(red[2], red[3]));
}

// ---- weight quantize: OIHW f32 -> [O][tap][I] i8 (in-wave max reduce) ------
__global__ void wquant_k(const float* __restrict__ w1, const float* __restrict__ w2,
                         const float* __restrict__ partial,
                         signed char* __restrict__ wq1, signed char* __restrict__ wq2) {
  const float* w = blockIdx.y ? w2 : w1;
  signed char* o = blockIdx.y ? wq2 : wq1;
  float pm = partial[blockIdx.y * 64 + (threadIdx.x & 63)];
  #pragma unroll
  for (int off = 32; off; off >>= 1) pm = fmaxf(pm, __shfl_xor(pm, off));
  float mt = tanhf(pm);
  int idx = blockIdx.x * 256 + threadIdx.x;
  int oo = idx / 2304, rr = idx % 2304, t9 = rr >> 8, ci = rr & 255;
  float t = tanhf(w[oo * 2304 + ci * 9 + t9]) / (2.f * mt) + 0.5f;
  int q = (int)rintf(t * 3.f);
  o[idx] = (signed char)(2 * q - 3);
}

// ---- act quantize + NCHW -> padded NHWC u8, coalesced; borders fused -------
__device__ __forceinline__ int border_pix(int bp) {  // 0..115 -> hh*30+ww
  int hh, ww;
  if (bp < 30)      { hh = 0;       ww = bp; }
  else if (bp < 60) { hh = 29;      ww = bp - 30; }
  else if (bp < 88) { hh = bp - 59; ww = 0; }
  else              { hh = bp - 87; ww = 29; }
  return hh * 30 + ww;
}

__global__ void aquant_k(const float* __restrict__ x, unsigned char* __restrict__ a1,
                         unsigned char* __restrict__ a2) {
  __shared__ unsigned au[784 * 17];  // [hw][16 u32 + pad]
  const int t = threadIdx.x;
  const int n = blockIdx.x >> 2, cq = blockIdx.x & 3;
  const int c4 = t >> 4, q = t & 15;

  #pragma unroll
  for (int m = 0; m < 2; ++m) {
    int s2 = t + m * 256;
    if (s2 < 464) {
      int bp = s2 >> 2, quad = s2 & 3;
      size_t off = ((size_t)n * 900 + border_pix(bp)) * 256 + cq * 64 + quad * 16;
      uint4 z = {0, 0, 0, 0};
      *(uint4*)(a1 + off) = z;
      *(uint4*)(a2 + off) = z;
    }
  }

  const float* xb = x + (size_t)n * 200704 + (cq * 64 + c4 * 4) * 784;
  #pragma unroll
  for (int k = 0; k < 13; ++k) {
    int hw4 = q + k * 16;
    if (hw4 < 196) {
      unsigned b[4][4];
      #pragma unroll
      for (int i = 0; i < 4; ++i) {
        float4 f = *(const float4*)(xb + i * 784 + hw4 * 4);
        b[i][0] = (unsigned)(int)rintf(3.f * fminf(fmaxf(f.x, 0.f), 1.f));
        b[i][1] = (unsigned)(int)rintf(3.f * fminf(fmaxf(f.y, 0.f), 1.f));
        b[i][2] = (unsigned)(int)rintf(3.f * fminf(fmaxf(f.z, 0.f), 1.f));
        b[i][3] = (unsigned)(int)rintf(3.f * fminf(fmaxf(f.w, 0.f), 1.f));
      }
      #pragma unroll
      for (int j = 0; j < 4; ++j)
        au[(hw4 * 4 + j) * 17 + c4] = b[0][j] | (b[1][j] << 8) | (b[2][j] << 16) | (b[3][j] << 24);
    }
  }
  __syncthreads();
  #pragma unroll
  for (int m = 0; m < 13; ++m) {
    int s = t + m * 256;
    if (s < 3136) {
      int pix = s >> 2, quad = s & 3;
      uint4 v;
      v.x = au[pix * 17 + quad * 4 + 0];
      v.y = au[pix * 17 + quad * 4 + 1];
      v.z = au[pix * 17 + quad * 4 + 2];
      v.w = au[pix * 17 + quad * 4 + 3];
      int hh = pix / 28, ww = pix - hh * 28;
      *(uint4*)(a1 + (((n * 30 + hh + 1) * 30) + ww + 1) * 256 + cq * 64 + quad * 16) = v;
    }
  }
}

// ---------------------------------------------------------------------------
// conv as implicit GEMM, 8-phase counted-vmcnt schedule.
// MODE 0: A=pixels, B=weights; epilogue BN1+ReLU+requant via u8 LDS transpose.
// MODE 1: A=weights, B=pixels; epilogue: chunked f32 LDS transpose (8 chunks
// of [2][16 c][256 pix], stride 264, dbuf), float4 xres + float4 fout.
// ---------------------------------------------------------------------------
#define PH_MID() do { __builtin_amdgcn_s_barrier(); \
  asm volatile("s_waitcnt lgkmcnt(0)" ::: "memory"); \
  __builtin_amdgcn_sched_barrier(0); \
  __builtin_amdgcn_s_setprio(1); } while (0)
#define PH_END() do { __builtin_amdgcn_s_setprio(0); \
  __builtin_amdgcn_s_barrier(); } while (0)
#define PH_ENDV(N) do { __builtin_amdgcn_s_setprio(0); \
  asm volatile("s_waitcnt vmcnt(" #N ")" ::: "memory"); \
  __builtin_amdgcn_sched_barrier(0); \
  __builtin_amdgcn_s_barrier(); } while (0)

template <int MODE>
__global__ __launch_bounds__(512, 2) void conv_gemm(
    const unsigned char* __restrict__ act, const signed char* __restrict__ wq,
    const float* __restrict__ sC, const float* __restrict__ tC,
    const float* __restrict__ xres, unsigned char* __restrict__ actout,
    float* __restrict__ fout) {
  extern __shared__ __align__(16) char lds[];
  const int tid = threadIdx.x, wv = tid >> 6, lane = tid & 63;
  // bijective XCD swizzle for 196 blocks (q=24, r=4)
  const int bswz = blockIdx.x & 7, bloc = blockIdx.x >> 3;
  const int wg = (bswz < 4 ? bswz * 25 : 100 + (bswz - 4) * 24) + bloc;
  const int pixBase = wg * 256;
  const int wvm = wv >> 2, wvn = wv & 3;
  constexpr int RAoff = (MODE == 0) ? 0 : 32768;
  constexpr int RBoff = 32768 - RAoff;

  int pixB[2][2], wB[2][2];
  {
    int s = (lane & 7) ^ ((lane >> 3) & 7);
    #pragma unroll
    for (int h = 0; h < 2; ++h)
      #pragma unroll
      for (int c = 0; c < 2; ++c) {
        int r = h * 128 + c * 64 + wv * 8 + (lane >> 3);
        int p = pixBase + r;
        int n = p / 784, rem = p % 784, hh = rem / 28, ww = rem % 28;
        pixB[h][c] = (((n * 30 + hh) * 30 + ww) << 8) + (s << 4);
        wB[h][c] = r * 2304 + (s << 4);
      }
  }
  auto tof = [](int kt) {
    int tap = kt >> 1;
    return ((tap / 3) * 30 + (tap % 3)) * 256 + ((kt & 1) << 7);
  };
  auto stagePix = [&](int h, int kt) {
    const int base = (kt & 1) * 65536 + h * 16384 + wv * 1024;
    const int toff = tof(kt);
    gload16(act + pixB[h][0] + toff, &lds[base]);
    gload16(act + pixB[h][1] + toff, &lds[base + 8192]);
  };
  auto stageW = [&](int h, int kt) {
    const int base = (kt & 1) * 65536 + 32768 + h * 16384 + wv * 1024;
    gload16(wq + wB[h][0] + kt * 128, &lds[base]);
    gload16(wq + wB[h][1] + kt * 128, &lds[base + 8192]);
  };
  auto stageA = [&](int h, int kt) { if (MODE == 0) stagePix(h, kt); else stageW(h, kt); };
  auto stageB = [&](int h, int kt) { if (MODE == 0) stageW(h, kt); else stagePix(h, kt); };

  i32x4 acc[8][4];
  #pragma unroll
  for (int i = 0; i < 8; ++i)
    #pragma unroll
    for (int j = 0; j < 4; ++j) acc[i][j] = (i32x4){0, 0, 0, 0};
  i32x4 pa[4][2], pb0[2][2], pb1[2][2];

  auto rdA = [&](int buf, int mh) {
    #pragma unroll
    for (int f = 0; f < 4; ++f) {
      int r = wvm * 128 + mh * 64 + f * 16 + (lane & 15);
      int rb = buf * 65536 + RAoff + r * 128;
      #pragma unroll
      for (int kc = 0; kc < 2; ++kc) {
        int sl = kc * 4 + (lane >> 4);
        pa[f][kc] = *(const i32x4*)&lds[rb + ((sl ^ (r & 7)) << 4)];
      }
    }
  };
  auto rdB = [&](int buf, int nh, i32x4 (*pb)[2]) {
    #pragma unroll
    for (int g = 0; g < 2; ++g) {
      int r = wvn * 64 + nh * 32 + g * 16 + (lane & 15);
      int rb = buf * 65536 + RBoff + r * 128;
      #pragma unroll
      for (int kc = 0; kc < 2; ++kc) {
        int sl = kc * 4 + (lane >> 4);
        pb[g][kc] = *(const i32x4*)&lds[rb + ((sl ^ (r & 7)) << 4)];
      }
    }
  };
  // kc OUTER: consecutive MFMAs hit different accumulators (dep distance 8)
  auto quad = [&](int mh, int nh, i32x4 (*pb)[2]) {
    #pragma unroll
    for (int kc = 0; kc < 2; ++kc)
      #pragma unroll
      for (int f = 0; f < 4; ++f)
        #pragma unroll
        for (int g = 0; g < 2; ++g)
          acc[mh * 4 + f][nh * 2 + g] = __builtin_amdgcn_mfma_i32_16x16x64_i8(
              pa[f][kc], pb[g][kc], acc[mh * 4 + f][nh * 2 + g], 0, 0, 0);
  };

  stageB(0, 0); stageA(0, 0); stageB(1, 0); stageA(1, 0);
  stageB(0, 1); stageA(0, 1); stageB(1, 1);
  asm volatile("s_waitcnt vmcnt(6)" ::: "memory");
  __builtin_amdgcn_sched_barrier(0);
  __builtin_amdgcn_s_barrier();

  for (int it = 0; it < 9; ++it) {
    const int ktY = 2 * it + 1, ktX2 = 2 * it + 2, ktY2 = 2 * it + 3;
    const bool st = (it < 8);
    rdA(0, 0); rdB(0, 0, pb0);
    stageA(1, ktY);
    PH_MID(); quad(0, 0, pb0); PH_END();
    rdB(0, 1, pb1);
    PH_MID(); quad(0, 1, pb1); PH_END();
    rdA(0, 1);
    if (st) stageB(0, ktX2);
    PH_MID(); quad(1, 0, pb0); PH_END();
    if (st) { stageA(0, ktX2); stageB(1, ktX2); }
    PH_MID(); quad(1, 1, pb1);
    if (st) { PH_ENDV(6); } else { PH_ENDV(0); }
    rdA(1, 0); rdB(1, 0, pb0);
    if (st) stageA(1, ktX2);
    PH_MID(); quad(0, 0, pb0); PH_END();
    rdB(1, 1, pb1);
    PH_MID(); quad(0, 1, pb1); PH_END();
    rdA(1, 1);
    if (st) stageB(0, ktY2);
    PH_MID(); quad(1, 0, pb0); PH_END();
    if (st) { stageA(0, ktY2); stageB(1, ktY2); }
    PH_MID(); quad(1, 1, pb1);
    PH_ENDV(6);
  }

  if (MODE == 0) {
    float sj[4], tj[4];
    #pragma unroll
    for (int j = 0; j < 4; ++j) {
      int c = wvn * 64 + j * 16 + (lane & 15);
      sj[j] = sC[c]; tj[j] = tC[c];
    }
    __syncthreads();
    #pragma unroll
    for (int i = 0; i < 8; ++i) {
      int lp0 = wvm * 128 + i * 16 + ((lane >> 4) << 2);
      #pragma unroll
      for (int j = 0; j < 4; ++j) {
        int lch = wvn * 64 + j * 16 + (lane & 15);
        #pragma unroll
        for (int r = 0; r < 4; ++r) {
          float y = (float)acc[i][j][r] * sj[j] + tj[j];
          y = fminf(fmaxf(y, 0.f), 1.f);
          int lp = lp0 + r;
          lds[lp * 256 + (lch ^ ((lp & 7) << 4))] = (char)(int)rintf(y * 3.f);
        }
      }
    }
    __syncthreads();
    int rr = tid >> 1, hf = tid & 1;
    int p = pixBase + rr;
    int n = p / 784, rem = p % 784, hh = rem / 28, ww = rem % 28;
    unsigned char* dst = actout + (((n * 30 + hh + 1) * 30 + (ww + 1)) << 8) + hf * 128;
    #pragma unroll
    for (int k = 0; k < 8; ++k) {
      uint4 v = *(const uint4*)&lds[rr * 256 + ((hf * 128 + k * 16) ^ ((rr & 7) << 4))];
      *(uint4*)(dst + k * 16) = v;
    }
  } else {
    float* ldsf = (float*)lds;
    const int half = tid >> 8, row = (tid >> 4) & 15, seg = tid & 15;
    #pragma unroll
    for (int s = 0; s < 8; ++s) {
      float* dst = ldsf + (s & 1) * 8448 + wvm * 4224;
      #pragma unroll
      for (int j = 0; j < 4; ++j)
        #pragma unroll
        for (int r = 0; r < 4; ++r)
          dst[(((lane >> 4) << 2) + r) * 264 + wvn * 64 + j * 16 + (lane & 15)] =
              (float)acc[s][j][r];
      __syncthreads();
      int c = half * 128 + s * 16 + row;
      float sc = sC[c], tc = tC[c];
      const float* src = ldsf + (s & 1) * 8448 + half * 4224 + row * 264 + seg * 16;
      const float* xrc = xres + (size_t)c * 784;
      float* foc = fout + (size_t)c * 784;
      #pragma unroll
      for (int f = 0; f < 4; ++f) {
        int p = pixBase + seg * 16 + f * 4;
        int n = p / 784, rem = p - n * 784;
        float4 v = *(const float4*)(src + f * 4);
        float4 xr = *(const float4*)(xrc + n * 200704 + rem);
        float4 y;
        y.x = fmaxf(v.x * sc + tc + xr.x, 0.f);
        y.y = fmaxf(v.y * sc + tc + xr.y, 0.f);
        y.z = fmaxf(v.z * sc + tc + xr.z, 0.f);
        y.w = fmaxf(v.w * sc + tc + xr.w, 0.f);
        *(float4*)(foc + n * 200704 + rem) = y;
      }
    }
  }
}

extern "C" void kernel_launch(void* const* d_in, const int* in_sizes, int n_in,
                              void* d_out, int out_size, void* d_ws, size_t ws_size,
                              hipStream_t stream) {
  const float* x  = (const float*)d_in[0];
  const float* w1 = (const float*)d_in[1];
  const float* g1 = (const float*)d_in[2];
  const float* b1 = (const float*)d_in[3];
  const float* m1 = (const float*)d_in[4];
  const float* v1 = (const float*)d_in[5];
  const float* w2 = (const float*)d_in[6];
  const float* g2 = (const float*)d_in[7];
  const float* b2 = (const float*)d_in[8];
  const float* m2 = (const float*)d_in[9];
  const float* v2 = (const float*)d_in[10];

  char* ws = (char*)d_ws;
  float* partial = (float*)ws;
  float* s1 = (float*)(ws + 1024);
  float* t1 = (float*)(ws + 2048);
  float* s2 = (float*)(ws + 3072);
  float* t2 = (float*)(ws + 4096);
  unsigned char* a1 = (unsigned char*)(ws + 8192);
  unsigned char* a2 = a1 + ABUF;
  signed char* wq1 = (signed char*)(a2 + ABUF);
  signed char* wq2 = wq1 + 589824;

  void (*k0)(const unsigned char*, const signed char*, const float*, const float*,
             const float*, unsigned char*, float*) = conv_gemm<0>;
  void (*k1)(const unsigned char*, const signed char*, const float*, const float*,
             const float*, unsigned char*, float*) = conv_gemm<1>;
  hipFuncSetAttribute((const void*)k0, hipFuncAttributeMaxDynamicSharedMemorySize, 131072);
  hipFuncSetAttribute((const void*)k1, hipFuncAttributeMaxDynamicSharedMemorySize, 131072);

  maxabs_k<<<dim3(64, 2), 256, 0, stream>>>(w1, w2, partial,
                                            g1, b1, m1, v1, g2, b2, m2, v2,
                                            s1, t1, s2, t2);
  wquant_k<<<dim3(2304, 2), 256, 0, stream>>>(w1, w2, partial, wq1, wq2);
  aquant_k<<<256, 256, 0, stream>>>(x, a1, a2);
  conv_gemm<0><<<196, 512, 131072, stream>>>(a1, wq1, s1, t1, nullptr, a2, nullptr);
  conv_gemm<1><<<196, 512, 131072, stream>>>(a2, wq2, s2, t2, x, nullptr, (float*)d_out);
}

// Round 5
// 204.638 us; speedup vs baseline: 1.0981x; 1.0805x over previous
//
#include <hip/hip_runtime.h>

// ---------------------------------------------------------------------------
// DoReFa BasicBlock on MI355X: both 3x3 convs as exact int8 implicit GEMM,
// 256x256 / 8-wave / 8-phase counted-vmcnt schedule (T2-T5).
//   acts   quantized to a_int in {0..3}       (value = a_int/3)
//   weights quantized to w_int in {-3,-1,1,3} (value = w_int/3)
//   conv_f32 = (sum a_int*w_int) / 9  -> folded into BN scale s = inv/9.
// Round 5: conv2 epilogue via DPP quad_perm 4x4 transpose -> float4 direct
// stores (no LDS, no barriers; r4's chunked-LDS epilogue regressed +6.5us
// with 602K bank conflicts). maxabs+prep fused into the aquant launch
// (5 -> 4 dispatches). wquant rewritten coalesced (LDS transpose, stride 9
// is bank-conflict-free). K-loop untouched.
// Workspace: [0,512) partial max f32[128]; s1/t1/s2/t2 @1024..5120;
// a1,a2 padded NHWC u8 [64][30][30][256]; wq1,wq2 i8 [256][9*256].
// ---------------------------------------------------------------------------

#define ABUF 14745600
using i32x4 = __attribute__((ext_vector_type(4))) int;

__device__ __forceinline__ void gload16(const void* g, void* l) {
  typedef const __attribute__((address_space(1))) unsigned int* gp_t;
  typedef __attribute__((address_space(3))) unsigned int* lp_t;
  __builtin_amdgcn_global_load_lds((gp_t)g, (lp_t)l, 16, 0, 0);
}

// ---- fused pre-pass: blocks 0-255 aquant, 256-383 maxabs partials ---------
__device__ __forceinline__ int border_pix(int bp) {  // 0..115 -> hh*30+ww
  int hh, ww;
  if (bp < 30)      { hh = 0;       ww = bp; }
  else if (bp < 60) { hh = 29;      ww = bp - 30; }
  else if (bp < 88) { hh = bp - 59; ww = 0; }
  else              { hh = bp - 87; ww = 29; }
  return hh * 30 + ww;
}

__global__ void pre_k(const float* __restrict__ x, unsigned char* __restrict__ a1,
                      unsigned char* __restrict__ a2,
                      const float* __restrict__ w1, const float* __restrict__ w2,
                      float* __restrict__ partial,
                      const float* g1, const float* b1, const float* m1, const float* v1,
                      const float* g2, const float* b2, const float* m2, const float* v2,
                      float* s1, float* t1, float* s2, float* t2) {
  const int t = threadIdx.x;
  if (blockIdx.x >= 256) {
    // ---- maxabs partials (64 blocks per tensor) + BN prep on block 256 ----
    int bx = blockIdx.x - 256;
    int ten = bx >> 6, bxl = bx & 63;
    if (ten == 0 && bxl == 0) {
      float i1 = g1[t] / sqrtf(v1[t] + 1e-5f);
      s1[t] = i1 * (1.f / 9.f);
      t1[t] = b1[t] - m1[t] * i1;
      float i2 = g2[t] / sqrtf(v2[t] + 1e-5f);
      s2[t] = i2 * (1.f / 9.f);
      t2[t] = b2[t] - m2[t] * i2;
    }
    const float4* v = (const float4*)(ten ? w2 : w1);
    float loc = 0.f;
    for (int i = bxl * 256 + t; i < 147456; i += 16384) {
      float4 f = v[i];
      loc = fmaxf(loc, fmaxf(fmaxf(fabsf(f.x), fabsf(f.y)), fmaxf(fabsf(f.z), fabsf(f.w))));
    }
    #pragma unroll
    for (int off = 32; off; off >>= 1) loc = fmaxf(loc, __shfl_xor(loc, off));
    __shared__ float red[4];
    if ((t & 63) == 0) red[t >> 6] = loc;
    __syncthreads();
    if (t == 0)
      partial[ten * 64 + bxl] = fmaxf(fmaxf(red[0], red[1]), fmaxf(red[2], red[3]));
    return;
  }
  // ---- act quantize + NCHW -> padded NHWC u8, borders fused ----
  __shared__ unsigned au[784 * 17];  // [hw][16 u32 + pad]
  const int n = blockIdx.x >> 2, cq = blockIdx.x & 3;
  const int c4 = t >> 4, q = t & 15;

  #pragma unroll
  for (int m = 0; m < 2; ++m) {
    int s2i = t + m * 256;
    if (s2i < 464) {
      int bp = s2i >> 2, quad = s2i & 3;
      size_t off = ((size_t)n * 900 + border_pix(bp)) * 256 + cq * 64 + quad * 16;
      uint4 z = {0, 0, 0, 0};
      *(uint4*)(a1 + off) = z;
      *(uint4*)(a2 + off) = z;
    }
  }

  const float* xb = x + (size_t)n * 200704 + (cq * 64 + c4 * 4) * 784;
  #pragma unroll
  for (int k = 0; k < 13; ++k) {
    int hw4 = q + k * 16;
    if (hw4 < 196) {
      unsigned b[4][4];
      #pragma unroll
      for (int i = 0; i < 4; ++i) {
        float4 f = *(const float4*)(xb + i * 784 + hw4 * 4);
        b[i][0] = (unsigned)(int)rintf(3.f * fminf(fmaxf(f.x, 0.f), 1.f));
        b[i][1] = (unsigned)(int)rintf(3.f * fminf(fmaxf(f.y, 0.f), 1.f));
        b[i][2] = (unsigned)(int)rintf(3.f * fminf(fmaxf(f.z, 0.f), 1.f));
        b[i][3] = (unsigned)(int)rintf(3.f * fminf(fmaxf(f.w, 0.f), 1.f));
      }
      #pragma unroll
      for (int j = 0; j < 4; ++j)
        au[(hw4 * 4 + j) * 17 + c4] = b[0][j] | (b[1][j] << 8) | (b[2][j] << 16) | (b[3][j] << 24);
    }
  }
  __syncthreads();
  #pragma unroll
  for (int m = 0; m < 13; ++m) {
    int s = t + m * 256;
    if (s < 3136) {
      int pix = s >> 2, quad = s & 3;
      uint4 v;
      v.x = au[pix * 17 + quad * 4 + 0];
      v.y = au[pix * 17 + quad * 4 + 1];
      v.z = au[pix * 17 + quad * 4 + 2];
      v.w = au[pix * 17 + quad * 4 + 3];
      int hh = pix / 28, ww = pix - hh * 28;
      *(uint4*)(a1 + (((n * 30 + hh + 1) * 30) + ww + 1) * 256 + cq * 64 + quad * 16) = v;
    }
  }
}

// ---- weight quantize, coalesced: block = one output channel ---------------
// Loads w[oo][0:2304] contiguously (tanh applied), LDS transpose read at
// stride 9 (9 coprime 32 -> conflict-free), contiguous i8 writes.
__global__ void wquant_k(const float* __restrict__ w1, const float* __restrict__ w2,
                         const float* __restrict__ partial,
                         signed char* __restrict__ wq1, signed char* __restrict__ wq2) {
  const int oo = blockIdx.x, ten = blockIdx.y;
  const float* w = ten ? w2 : w1;
  signed char* o = ten ? wq2 : wq1;
  __shared__ float wl[2304];
  const int t = threadIdx.x;
  float pm = partial[ten * 64 + (t & 63)];
  #pragma unroll
  for (int off = 32; off; off >>= 1) pm = fmaxf(pm, __shfl_xor(pm, off));
  const float inv = 1.f / (2.f * tanhf(pm));
  #pragma unroll
  for (int k = 0; k < 9; ++k) wl[k * 256 + t] = tanhf(w[oo * 2304 + k * 256 + t]);
  __syncthreads();
  #pragma unroll
  for (int k = 0; k < 9; ++k) {
    int j = k * 256 + t, t9 = j >> 8, ci = j & 255;
    float tt = wl[ci * 9 + t9] * inv + 0.5f;
    int q = (int)rintf(tt * 3.f);
    o[oo * 2304 + j] = (signed char)(2 * q - 3);
  }
}

// ---------------------------------------------------------------------------
// conv as implicit GEMM, 8-phase counted-vmcnt schedule.
// MODE 0: A=pixels, B=weights; epilogue BN1+ReLU+requant via u8 LDS transpose.
// MODE 1: A=weights, B=pixels; epilogue: DPP quad_perm 4x4 (c x pixel)
// transpose in-register -> BN2+residual+ReLU -> float4 stores, no LDS.
// ---------------------------------------------------------------------------
#define PH_MID() do { __builtin_amdgcn_s_barrier(); \
  asm volatile("s_waitcnt lgkmcnt(0)" ::: "memory"); \
  __builtin_amdgcn_sched_barrier(0); \
  __builtin_amdgcn_s_setprio(1); } while (0)
#define PH_END() do { __builtin_amdgcn_s_setprio(0); \
  __builtin_amdgcn_s_barrier(); } while (0)
#define PH_ENDV(N) do { __builtin_amdgcn_s_setprio(0); \
  asm volatile("s_waitcnt vmcnt(" #N ")" ::: "memory"); \
  __builtin_amdgcn_sched_barrier(0); \
  __builtin_amdgcn_s_barrier(); } while (0)

template <int MODE>
__global__ __launch_bounds__(512, 2) void conv_gemm(
    const unsigned char* __restrict__ act, const signed char* __restrict__ wq,
    const float* __restrict__ sC, const float* __restrict__ tC,
    const float* __restrict__ xres, unsigned char* __restrict__ actout,
    float* __restrict__ fout) {
  extern __shared__ __align__(16) char lds[];
  const int tid = threadIdx.x, wv = tid >> 6, lane = tid & 63;
  // bijective XCD swizzle for 196 blocks (q=24, r=4)
  const int bswz = blockIdx.x & 7, bloc = blockIdx.x >> 3;
  const int wg = (bswz < 4 ? bswz * 25 : 100 + (bswz - 4) * 24) + bloc;
  const int pixBase = wg * 256;
  const int wvm = wv >> 2, wvn = wv & 3;
  constexpr int RAoff = (MODE == 0) ? 0 : 32768;
  constexpr int RBoff = 32768 - RAoff;

  int pixB[2][2], wB[2][2];
  {
    int s = (lane & 7) ^ ((lane >> 3) & 7);
    #pragma unroll
    for (int h = 0; h < 2; ++h)
      #pragma unroll
      for (int c = 0; c < 2; ++c) {
        int r = h * 128 + c * 64 + wv * 8 + (lane >> 3);
        int p = pixBase + r;
        int n = p / 784, rem = p % 784, hh = rem / 28, ww = rem % 28;
        pixB[h][c] = (((n * 30 + hh) * 30 + ww) << 8) + (s << 4);
        wB[h][c] = r * 2304 + (s << 4);
      }
  }
  auto tof = [](int kt) {
    int tap = kt >> 1;
    return ((tap / 3) * 30 + (tap % 3)) * 256 + ((kt & 1) << 7);
  };
  auto stagePix = [&](int h, int kt) {
    const int base = (kt & 1) * 65536 + h * 16384 + wv * 1024;
    const int toff = tof(kt);
    gload16(act + pixB[h][0] + toff, &lds[base]);
    gload16(act + pixB[h][1] + toff, &lds[base + 8192]);
  };
  auto stageW = [&](int h, int kt) {
    const int base = (kt & 1) * 65536 + 32768 + h * 16384 + wv * 1024;
    gload16(wq + wB[h][0] + kt * 128, &lds[base]);
    gload16(wq + wB[h][1] + kt * 128, &lds[base + 8192]);
  };
  auto stageA = [&](int h, int kt) { if (MODE == 0) stagePix(h, kt); else stageW(h, kt); };
  auto stageB = [&](int h, int kt) { if (MODE == 0) stageW(h, kt); else stagePix(h, kt); };

  i32x4 acc[8][4];
  #pragma unroll
  for (int i = 0; i < 8; ++i)
    #pragma unroll
    for (int j = 0; j < 4; ++j) acc[i][j] = (i32x4){0, 0, 0, 0};
  i32x4 pa[4][2], pb0[2][2], pb1[2][2];

  auto rdA = [&](int buf, int mh) {
    #pragma unroll
    for (int f = 0; f < 4; ++f) {
      int r = wvm * 128 + mh * 64 + f * 16 + (lane & 15);
      int rb = buf * 65536 + RAoff + r * 128;
      #pragma unroll
      for (int kc = 0; kc < 2; ++kc) {
        int sl = kc * 4 + (lane >> 4);
        pa[f][kc] = *(const i32x4*)&lds[rb + ((sl ^ (r & 7)) << 4)];
      }
    }
  };
  auto rdB = [&](int buf, int nh, i32x4 (*pb)[2]) {
    #pragma unroll
    for (int g = 0; g < 2; ++g) {
      int r = wvn * 64 + nh * 32 + g * 16 + (lane & 15);
      int rb = buf * 65536 + RBoff + r * 128;
      #pragma unroll
      for (int kc = 0; kc < 2; ++kc) {
        int sl = kc * 4 + (lane >> 4);
        pb[g][kc] = *(const i32x4*)&lds[rb + ((sl ^ (r & 7)) << 4)];
      }
    }
  };
  auto quad = [&](int mh, int nh, i32x4 (*pb)[2]) {
    #pragma unroll
    for (int kc = 0; kc < 2; ++kc)
      #pragma unroll
      for (int f = 0; f < 4; ++f)
        #pragma unroll
        for (int g = 0; g < 2; ++g)
          acc[mh * 4 + f][nh * 2 + g] = __builtin_amdgcn_mfma_i32_16x16x64_i8(
              pa[f][kc], pb[g][kc], acc[mh * 4 + f][nh * 2 + g], 0, 0, 0);
  };

  stageB(0, 0); stageA(0, 0); stageB(1, 0); stageA(1, 0);
  stageB(0, 1); stageA(0, 1); stageB(1, 1);
  asm volatile("s_waitcnt vmcnt(6)" ::: "memory");
  __builtin_amdgcn_sched_barrier(0);
  __builtin_amdgcn_s_barrier();

  for (int it = 0; it < 9; ++it) {
    const int ktY = 2 * it + 1, ktX2 = 2 * it + 2, ktY2 = 2 * it + 3;
    const bool st = (it < 8);
    rdA(0, 0); rdB(0, 0, pb0);
    stageA(1, ktY);
    PH_MID(); quad(0, 0, pb0); PH_END();
    rdB(0, 1, pb1);
    PH_MID(); quad(0, 1, pb1); PH_END();
    rdA(0, 1);
    if (st) stageB(0, ktX2);
    PH_MID(); quad(1, 0, pb0); PH_END();
    if (st) { stageA(0, ktX2); stageB(1, ktX2); }
    PH_MID(); quad(1, 1, pb1);
    if (st) { PH_ENDV(6); } else { PH_ENDV(0); }
    rdA(1, 0); rdB(1, 0, pb0);
    if (st) stageA(1, ktX2);
    PH_MID(); quad(0, 0, pb0); PH_END();
    rdB(1, 1, pb1);
    PH_MID(); quad(0, 1, pb1); PH_END();
    rdA(1, 1);
    if (st) stageB(0, ktY2);
    PH_MID(); quad(1, 0, pb0); PH_END();
    if (st) { stageA(0, ktY2); stageB(1, ktY2); }
    PH_MID(); quad(1, 1, pb1);
    PH_ENDV(6);
  }

  if (MODE == 0) {
    // BN1 + ReLU + requant; u8 LDS transpose -> coalesced 16B stores
    float sj[4], tj[4];
    #pragma unroll
    for (int j = 0; j < 4; ++j) {
      int c = wvn * 64 + j * 16 + (lane & 15);
      sj[j] = sC[c]; tj[j] = tC[c];
    }
    __syncthreads();
    #pragma unroll
    for (int i = 0; i < 8; ++i) {
      int lp0 = wvm * 128 + i * 16 + ((lane >> 4) << 2);
      #pragma unroll
      for (int j = 0; j < 4; ++j) {
        int lch = wvn * 64 + j * 16 + (lane & 15);
        #pragma unroll
        for (int r = 0; r < 4; ++r) {
          float y = (float)acc[i][j][r] * sj[j] + tj[j];
          y = fminf(fmaxf(y, 0.f), 1.f);
          int lp = lp0 + r;
          lds[lp * 256 + (lch ^ ((lp & 7) << 4))] = (char)(int)rintf(y * 3.f);
        }
      }
    }
    __syncthreads();
    int rr = tid >> 1, hf = tid & 1;
    int p = pixBase + rr;
    int n = p / 784, rem = p % 784, hh = rem / 28, ww = rem % 28;
    unsigned char* dst = actout + (((n * 30 + hh + 1) * 30 + (ww + 1)) << 8) + hf * 128;
    #pragma unroll
    for (int k = 0; k < 8; ++k) {
      uint4 v = *(const uint4*)&lds[rr * 256 + ((hf * 128 + k * 16) ^ ((rr & 7) << 4))];
      *(uint4*)(dst + k * 16) = v;
    }
  } else {
    // BN2 + residual + ReLU. Each lane-quad holds a 4x4 (c x pixel) tile:
    // lane l, reg r -> c = base_c + r, pixel = base_p + (l&3). Two-stage
    // DPP quad_perm butterfly transposes it so each lane holds one c and
    // 4 consecutive pixels -> float4 load/store (64B contiguous per quad).
    #pragma unroll
    for (int i = 0; i < 8; ++i) {
      int c = wvm * 128 + i * 16 + ((lane >> 4) << 2) + (lane & 3);
      float sc = sC[c], tc = tC[c];
      #pragma unroll
      for (int j = 0; j < 4; ++j) {
        int a0 = acc[i][j][0], a1 = acc[i][j][1], a2 = acc[i][j][2], a3 = acc[i][j][3];
        // stage 1: XOR-1 butterfly (quad_perm [1,0,3,2] = 0xB1)
        int t0 = __builtin_amdgcn_mov_dpp(a0, 0xB1, 0xF, 0xF, true);
        int t1 = __builtin_amdgcn_mov_dpp(a1, 0xB1, 0xF, 0xF, true);
        int t2 = __builtin_amdgcn_mov_dpp(a2, 0xB1, 0xF, 0xF, true);
        int t3 = __builtin_amdgcn_mov_dpp(a3, 0xB1, 0xF, 0xF, true);
        const bool o1 = (lane & 1) != 0;
        int v0 = o1 ? t1 : a0;
        int v1 = o1 ? a1 : t0;
        int v2 = o1 ? t3 : a2;
        int v3 = o1 ? a3 : t2;
        // stage 2: XOR-2 butterfly (quad_perm [2,3,0,1] = 0x4E)
        int u0 = __builtin_amdgcn_mov_dpp(v2, 0x4E, 0xF, 0xF, true);
        int u1 = __builtin_amdgcn_mov_dpp(v3, 0x4E, 0xF, 0xF, true);
        int u2 = __builtin_amdgcn_mov_dpp(v0, 0x4E, 0xF, 0xF, true);
        int u3 = __builtin_amdgcn_mov_dpp(v1, 0x4E, 0xF, 0xF, true);
        const bool o2 = (lane & 2) != 0;
        int z0 = o2 ? u0 : v0;
        int z1 = o2 ? u1 : v1;
        int z2 = o2 ? v2 : u2;
        int z3 = o2 ? v3 : u3;
        int P = pixBase + wvn * 64 + j * 16 + (lane & 12);
        int n = P / 784, rem = P - n * 784;   // 784%4==0 -> float4 never crosses
        size_t addr = (size_t)n * 200704 + (size_t)c * 784 + rem;
        float4 xr = *(const float4*)(xres + addr);
        float4 y;
        y.x = fmaxf((float)z0 * sc + tc + xr.x, 0.f);
        y.y = fmaxf((float)z1 * sc + tc + xr.y, 0.f);
        y.z = fmaxf((float)z2 * sc + tc + xr.z, 0.f);
        y.w = fmaxf((float)z3 * sc + tc + xr.w, 0.f);
        *(float4*)(fout + addr) = y;
      }
    }
  }
}

extern "C" void kernel_launch(void* const* d_in, const int* in_sizes, int n_in,
                              void* d_out, int out_size, void* d_ws, size_t ws_size,
                              hipStream_t stream) {
  const float* x  = (const float*)d_in[0];
  const float* w1 = (const float*)d_in[1];
  const float* g1 = (const float*)d_in[2];
  const float* b1 = (const float*)d_in[3];
  const float* m1 = (const float*)d_in[4];
  const float* v1 = (const float*)d_in[5];
  const float* w2 = (const float*)d_in[6];
  const float* g2 = (const float*)d_in[7];
  const float* b2 = (const float*)d_in[8];
  const float* m2 = (const float*)d_in[9];
  const float* v2 = (const float*)d_in[10];

  char* ws = (char*)d_ws;
  float* partial = (float*)ws;
  float* s1 = (float*)(ws + 1024);
  float* t1 = (float*)(ws + 2048);
  float* s2 = (float*)(ws + 3072);
  float* t2 = (float*)(ws + 4096);
  unsigned char* a1 = (unsigned char*)(ws + 8192);
  unsigned char* a2 = a1 + ABUF;
  signed char* wq1 = (signed char*)(a2 + ABUF);
  signed char* wq2 = wq1 + 589824;

  void (*k0)(const unsigned char*, const signed char*, const float*, const float*,
             const float*, unsigned char*, float*) = conv_gemm<0>;
  void (*k1)(const unsigned char*, const signed char*, const float*, const float*,
             const float*, unsigned char*, float*) = conv_gemm<1>;
  hipFuncSetAttribute((const void*)k0, hipFuncAttributeMaxDynamicSharedMemorySize, 131072);
  hipFuncSetAttribute((const void*)k1, hipFuncAttributeMaxDynamicSharedMemorySize, 131072);

  pre_k<<<384, 256, 0, stream>>>(x, a1, a2, w1, w2, partial,
                                 g1, b1, m1, v1, g2, b2, m2, v2, s1, t1, s2, t2);
  wquant_k<<<dim3(256, 2), 256, 0, stream>>>(w1, w2, partial, wq1, wq2);
  conv_gemm<0><<<196, 512, 131072, stream>>>(a1, wq1, s1, t1, nullptr, a2, nullptr);
  conv_gemm<1><<<196, 512, 131072, stream>>>(a2, wq2, s2, t2, x, nullptr, (float*)d_out);
}

// Round 6
// 198.126 us; speedup vs baseline: 1.1342x; 1.0329x over previous
//
#include <hip/hip_runtime.h>

// ---------------------------------------------------------------------------
// DoReFa BasicBlock on MI355X: both 3x3 convs as exact int8 implicit GEMM.
//   acts   quantized to a_int in {0..3}       (value = a_int/3)
//   weights quantized to w_int in {-3,-1,1,3} (value = w_int/3)
//   conv_f32 = (sum a_int*w_int) / 9  -> folded into BN scale s = inv/9.
// Round 6: de-lockstepped K-loop. r2-r5 showed every barrier-lockstep
// schedule pins at ~50us/21% MfmaUtil because the per-phase barriers force
// the CU's LDS-read pipe (~1150 cyc/phase for 8 waves) and the MFMA pipe
// (~650 cyc/phase) to ALTERNATE. New loop: ONE barrier per K-tile (the
// buffer-handoff: collective vmcnt + read/write fence); within a tile,
// counted lgkmcnt waits only -> waves drift, LDS reads stream under MFMAs.
//   per tile/wave: rd{pa0,pb0,pb1}(16) | lgkm(4) quad00 | lgkm(0) quad01 |
//   rd pa1(8) | vmcnt(0)+lgkm(0); s_barrier; stage(t+2) | quad10 quad11.
// Ledger: stage(t) issued after bar_{t-2}, drained by own vmcnt(0) at
// bar_{t-1}, collective at bar_{t-1} -> reads(t) valid. All reads of buf b
// drain pre-barrier before any wave restages b. Barriers: 144 -> 18+1.
// Workspace: [0,512) partial max f32[128]; s1/t1/s2/t2 @1024..5120;
// a1,a2 padded NHWC u8 [64][30][30][256]; wq1,wq2 i8 [256][9*256].
// ---------------------------------------------------------------------------

#define ABUF 14745600
using i32x4 = __attribute__((ext_vector_type(4))) int;

__device__ __forceinline__ void gload16(const void* g, void* l) {
  typedef const __attribute__((address_space(1))) unsigned int* gp_t;
  typedef __attribute__((address_space(3))) unsigned int* lp_t;
  __builtin_amdgcn_global_load_lds((gp_t)g, (lp_t)l, 16, 0, 0);
}

// ---- fused pre-pass: blocks 0-255 aquant, 256-383 maxabs partials ---------
__device__ __forceinline__ int border_pix(int bp) {  // 0..115 -> hh*30+ww
  int hh, ww;
  if (bp < 30)      { hh = 0;       ww = bp; }
  else if (bp < 60) { hh = 29;      ww = bp - 30; }
  else if (bp < 88) { hh = bp - 59; ww = 0; }
  else              { hh = bp - 87; ww = 29; }
  return hh * 30 + ww;
}

__global__ void pre_k(const float* __restrict__ x, unsigned char* __restrict__ a1,
                      unsigned char* __restrict__ a2,
                      const float* __restrict__ w1, const float* __restrict__ w2,
                      float* __restrict__ partial,
                      const float* g1, const float* b1, const float* m1, const float* v1,
                      const float* g2, const float* b2, const float* m2, const float* v2,
                      float* s1, float* t1, float* s2, float* t2) {
  const int t = threadIdx.x;
  if (blockIdx.x >= 256) {
    int bx = blockIdx.x - 256;
    int ten = bx >> 6, bxl = bx & 63;
    if (ten == 0 && bxl == 0) {
      float i1 = g1[t] / sqrtf(v1[t] + 1e-5f);
      s1[t] = i1 * (1.f / 9.f);
      t1[t] = b1[t] - m1[t] * i1;
      float i2 = g2[t] / sqrtf(v2[t] + 1e-5f);
      s2[t] = i2 * (1.f / 9.f);
      t2[t] = b2[t] - m2[t] * i2;
    }
    const float4* v = (const float4*)(ten ? w2 : w1);
    float loc = 0.f;
    for (int i = bxl * 256 + t; i < 147456; i += 16384) {
      float4 f = v[i];
      loc = fmaxf(loc, fmaxf(fmaxf(fabsf(f.x), fabsf(f.y)), fmaxf(fabsf(f.z), fabsf(f.w))));
    }
    #pragma unroll
    for (int off = 32; off; off >>= 1) loc = fmaxf(loc, __shfl_xor(loc, off));
    __shared__ float red[4];
    if ((t & 63) == 0) red[t >> 6] = loc;
    __syncthreads();
    if (t == 0)
      partial[ten * 64 + bxl] = fmaxf(fmaxf(red[0], red[1]), fmaxf(red[2], red[3]));
    return;
  }
  __shared__ unsigned au[784 * 17];
  const int n = blockIdx.x >> 2, cq = blockIdx.x & 3;
  const int c4 = t >> 4, q = t & 15;

  #pragma unroll
  for (int m = 0; m < 2; ++m) {
    int s2i = t + m * 256;
    if (s2i < 464) {
      int bp = s2i >> 2, quad = s2i & 3;
      size_t off = ((size_t)n * 900 + border_pix(bp)) * 256 + cq * 64 + quad * 16;
      uint4 z = {0, 0, 0, 0};
      *(uint4*)(a1 + off) = z;
      *(uint4*)(a2 + off) = z;
    }
  }

  const float* xb = x + (size_t)n * 200704 + (cq * 64 + c4 * 4) * 784;
  #pragma unroll
  for (int k = 0; k < 13; ++k) {
    int hw4 = q + k * 16;
    if (hw4 < 196) {
      unsigned b[4][4];
      #pragma unroll
      for (int i = 0; i < 4; ++i) {
        float4 f = *(const float4*)(xb + i * 784 + hw4 * 4);
        b[i][0] = (unsigned)(int)rintf(3.f * fminf(fmaxf(f.x, 0.f), 1.f));
        b[i][1] = (unsigned)(int)rintf(3.f * fminf(fmaxf(f.y, 0.f), 1.f));
        b[i][2] = (unsigned)(int)rintf(3.f * fminf(fmaxf(f.z, 0.f), 1.f));
        b[i][3] = (unsigned)(int)rintf(3.f * fminf(fmaxf(f.w, 0.f), 1.f));
      }
      #pragma unroll
      for (int j = 0; j < 4; ++j)
        au[(hw4 * 4 + j) * 17 + c4] = b[0][j] | (b[1][j] << 8) | (b[2][j] << 16) | (b[3][j] << 24);
    }
  }
  __syncthreads();
  #pragma unroll
  for (int m = 0; m < 13; ++m) {
    int s = t + m * 256;
    if (s < 3136) {
      int pix = s >> 2, quad = s & 3;
      uint4 v;
      v.x = au[pix * 17 + quad * 4 + 0];
      v.y = au[pix * 17 + quad * 4 + 1];
      v.z = au[pix * 17 + quad * 4 + 2];
      v.w = au[pix * 17 + quad * 4 + 3];
      int hh = pix / 28, ww = pix - hh * 28;
      *(uint4*)(a1 + (((n * 30 + hh + 1) * 30) + ww + 1) * 256 + cq * 64 + quad * 16) = v;
    }
  }
}

// ---- weight quantize, coalesced: block = one output channel ---------------
__global__ void wquant_k(const float* __restrict__ w1, const float* __restrict__ w2,
                         const float* __restrict__ partial,
                         signed char* __restrict__ wq1, signed char* __restrict__ wq2) {
  const int oo = blockIdx.x, ten = blockIdx.y;
  const float* w = ten ? w2 : w1;
  signed char* o = ten ? wq2 : wq1;
  __shared__ float wl[2304];
  const int t = threadIdx.x;
  float pm = partial[ten * 64 + (t & 63)];
  #pragma unroll
  for (int off = 32; off; off >>= 1) pm = fmaxf(pm, __shfl_xor(pm, off));
  const float inv = 1.f / (2.f * tanhf(pm));
  #pragma unroll
  for (int k = 0; k < 9; ++k) wl[k * 256 + t] = tanhf(w[oo * 2304 + k * 256 + t]);
  __syncthreads();
  #pragma unroll
  for (int k = 0; k < 9; ++k) {
    int j = k * 256 + t, t9 = j >> 8, ci = j & 255;
    float tt = wl[ci * 9 + t9] * inv + 0.5f;
    int q = (int)rintf(tt * 3.f);
    o[oo * 2304 + j] = (signed char)(2 * q - 3);
  }
}

// ---------------------------------------------------------------------------
// conv as implicit GEMM, de-lockstepped 1-barrier-per-K-tile schedule.
// MODE 0: A=pixels, B=weights; epilogue BN1+ReLU+requant via u8 LDS transpose.
// MODE 1: A=weights, B=pixels; epilogue DPP 4x4 transpose -> float4 stores.
// ---------------------------------------------------------------------------
#define LGKM(N) do { asm volatile("s_waitcnt lgkmcnt(" #N ")" ::: "memory"); \
  __builtin_amdgcn_sched_barrier(0); } while (0)
#define SBAR0() __builtin_amdgcn_sched_barrier(0)

template <int MODE>
__global__ __launch_bounds__(512, 2) void conv_gemm(
    const unsigned char* __restrict__ act, const signed char* __restrict__ wq,
    const float* __restrict__ sC, const float* __restrict__ tC,
    const float* __restrict__ xres, unsigned char* __restrict__ actout,
    float* __restrict__ fout) {
  extern __shared__ __align__(16) char lds[];
  const int tid = threadIdx.x, wv = tid >> 6, lane = tid & 63;
  // bijective XCD swizzle for 196 blocks (q=24, r=4)
  const int bswz = blockIdx.x & 7, bloc = blockIdx.x >> 3;
  const int wg = (bswz < 4 ? bswz * 25 : 100 + (bswz - 4) * 24) + bloc;
  const int pixBase = wg * 256;
  const int wvm = wv >> 2, wvn = wv & 3;
  constexpr int RAoff = (MODE == 0) ? 0 : 32768;
  constexpr int RBoff = 32768 - RAoff;

  int pixB[2][2], wB[2][2];
  {
    int s = (lane & 7) ^ ((lane >> 3) & 7);
    #pragma unroll
    for (int h = 0; h < 2; ++h)
      #pragma unroll
      for (int c = 0; c < 2; ++c) {
        int r = h * 128 + c * 64 + wv * 8 + (lane >> 3);
        int p = pixBase + r;
        int n = p / 784, rem = p % 784, hh = rem / 28, ww = rem % 28;
        pixB[h][c] = (((n * 30 + hh) * 30 + ww) << 8) + (s << 4);
        wB[h][c] = r * 2304 + (s << 4);
      }
  }
  auto tof = [](int kt) {
    int tap = kt >> 1;
    return ((tap / 3) * 30 + (tap % 3)) * 256 + ((kt & 1) << 7);
  };
  auto stagePix = [&](int h, int kt) {
    const int base = (kt & 1) * 65536 + h * 16384 + wv * 1024;
    const int toff = tof(kt);
    gload16(act + pixB[h][0] + toff, &lds[base]);
    gload16(act + pixB[h][1] + toff, &lds[base + 8192]);
  };
  auto stageW = [&](int h, int kt) {
    const int base = (kt & 1) * 65536 + 32768 + h * 16384 + wv * 1024;
    gload16(wq + wB[h][0] + kt * 128, &lds[base]);
    gload16(wq + wB[h][1] + kt * 128, &lds[base + 8192]);
  };
  auto stageT = [&](int kt) {
    if (MODE == 0) { stagePix(0, kt); stagePix(1, kt); stageW(0, kt); stageW(1, kt); }
    else           { stageW(0, kt); stageW(1, kt); stagePix(0, kt); stagePix(1, kt); }
  };

  i32x4 acc[8][4];
  #pragma unroll
  for (int i = 0; i < 8; ++i)
    #pragma unroll
    for (int j = 0; j < 4; ++j) acc[i][j] = (i32x4){0, 0, 0, 0};
  i32x4 pa[4][2], pb0[2][2], pb1[2][2];

  auto rdA = [&](int buf, int mh) {
    #pragma unroll
    for (int f = 0; f < 4; ++f) {
      int r = wvm * 128 + mh * 64 + f * 16 + (lane & 15);
      int rb = buf * 65536 + RAoff + r * 128;
      #pragma unroll
      for (int kc = 0; kc < 2; ++kc) {
        int sl = kc * 4 + (lane >> 4);
        pa[f][kc] = *(const i32x4*)&lds[rb + ((sl ^ (r & 7)) << 4)];
      }
    }
  };
  auto rdB = [&](int buf, int nh, i32x4 (*pb)[2]) {
    #pragma unroll
    for (int g = 0; g < 2; ++g) {
      int r = wvn * 64 + nh * 32 + g * 16 + (lane & 15);
      int rb = buf * 65536 + RBoff + r * 128;
      #pragma unroll
      for (int kc = 0; kc < 2; ++kc) {
        int sl = kc * 4 + (lane >> 4);
        pb[g][kc] = *(const i32x4*)&lds[rb + ((sl ^ (r & 7)) << 4)];
      }
    }
  };
  auto quad = [&](int mh, int nh, i32x4 (*pb)[2]) {
    #pragma unroll
    for (int kc = 0; kc < 2; ++kc)
      #pragma unroll
      for (int f = 0; f < 4; ++f)
        #pragma unroll
        for (int g = 0; g < 2; ++g)
          acc[mh * 4 + f][nh * 2 + g] = __builtin_amdgcn_mfma_i32_16x16x64_i8(
              pa[f][kc], pb[g][kc], acc[mh * 4 + f][nh * 2 + g], 0, 0, 0);
  };

  // prologue: stage tiles 0 and 1; wait tile 0 landed (collective at barrier)
  stageT(0); stageT(1);
  asm volatile("s_waitcnt vmcnt(8)" ::: "memory");
  SBAR0();
  __builtin_amdgcn_s_barrier();
  asm volatile("" ::: "memory");

  for (int t = 0; t < 18; ++t) {
    const int buf = t & 1;
    // read burst 1: pa(mh=0) + pb0, then pb1 (order pinned for lgkm counts)
    rdA(buf, 0); rdB(buf, 0, pb0);
    SBAR0();
    rdB(buf, 1, pb1);
    LGKM(4);   // pa0+pb0 done (pb1's 4 may remain)
    __builtin_amdgcn_s_setprio(1); quad(0, 0, pb0); __builtin_amdgcn_s_setprio(0);
    LGKM(0);   // pb1 done
    __builtin_amdgcn_s_setprio(1); quad(0, 1, pb1); __builtin_amdgcn_s_setprio(0);
    // read burst 2: pa(mh=1) into same regs (after quad(0,*) consumed pa0)
    rdA(buf, 1);
    if (t < 17) {
      // tile handoff: my buf-t reads drained + my stage(t+1) loads landed;
      // barrier makes both collective; then buf is safe to restage.
      asm volatile("s_waitcnt vmcnt(0) lgkmcnt(0)" ::: "memory");
      SBAR0();
      __builtin_amdgcn_s_barrier();
      asm volatile("" ::: "memory");
      if (t < 16) stageT(t + 2);
    } else {
      LGKM(0);
    }
    __builtin_amdgcn_s_setprio(1);
    quad(1, 0, pb0); quad(1, 1, pb1);
    __builtin_amdgcn_s_setprio(0);
  }

  if (MODE == 0) {
    // BN1 + ReLU + requant; u8 LDS transpose -> coalesced 16B stores
    float sj[4], tj[4];
    #pragma unroll
    for (int j = 0; j < 4; ++j) {
      int c = wvn * 64 + j * 16 + (lane & 15);
      sj[j] = sC[c]; tj[j] = tC[c];
    }
    __syncthreads();
    #pragma unroll
    for (int i = 0; i < 8; ++i) {
      int lp0 = wvm * 128 + i * 16 + ((lane >> 4) << 2);
      #pragma unroll
      for (int j = 0; j < 4; ++j) {
        int lch = wvn * 64 + j * 16 + (lane & 15);
        #pragma unroll
        for (int r = 0; r < 4; ++r) {
          float y = (float)acc[i][j][r] * sj[j] + tj[j];
          y = fminf(fmaxf(y, 0.f), 1.f);
          int lp = lp0 + r;
          lds[lp * 256 + (lch ^ ((lp & 7) << 4))] = (char)(int)rintf(y * 3.f);
        }
      }
    }
    __syncthreads();
    int rr = tid >> 1, hf = tid & 1;
    int p = pixBase + rr;
    int n = p / 784, rem = p % 784, hh = rem / 28, ww = rem % 28;
    unsigned char* dst = actout + (((n * 30 + hh + 1) * 30 + (ww + 1)) << 8) + hf * 128;
    #pragma unroll
    for (int k = 0; k < 8; ++k) {
      uint4 v = *(const uint4*)&lds[rr * 256 + ((hf * 128 + k * 16) ^ ((rr & 7) << 4))];
      *(uint4*)(dst + k * 16) = v;
    }
  } else {
    // BN2 + residual + ReLU via DPP quad_perm 4x4 transpose -> float4 I/O
    #pragma unroll
    for (int i = 0; i < 8; ++i) {
      int c = wvm * 128 + i * 16 + ((lane >> 4) << 2) + (lane & 3);
      float sc = sC[c], tc = tC[c];
      #pragma unroll
      for (int j = 0; j < 4; ++j) {
        int a0 = acc[i][j][0], a1 = acc[i][j][1], a2 = acc[i][j][2], a3 = acc[i][j][3];
        int t0 = __builtin_amdgcn_mov_dpp(a0, 0xB1, 0xF, 0xF, true);
        int t1 = __builtin_amdgcn_mov_dpp(a1, 0xB1, 0xF, 0xF, true);
        int t2 = __builtin_amdgcn_mov_dpp(a2, 0xB1, 0xF, 0xF, true);
        int t3 = __builtin_amdgcn_mov_dpp(a3, 0xB1, 0xF, 0xF, true);
        const bool o1 = (lane & 1) != 0;
        int v0 = o1 ? t1 : a0;
        int v1 = o1 ? a1 : t0;
        int v2 = o1 ? t3 : a2;
        int v3 = o1 ? a3 : t2;
        int u0 = __builtin_amdgcn_mov_dpp(v2, 0x4E, 0xF, 0xF, true);
        int u1 = __builtin_amdgcn_mov_dpp(v3, 0x4E, 0xF, 0xF, true);
        int u2 = __builtin_amdgcn_mov_dpp(v0, 0x4E, 0xF, 0xF, true);
        int u3 = __builtin_amdgcn_mov_dpp(v1, 0x4E, 0xF, 0xF, true);
        const bool o2 = (lane & 2) != 0;
        int z0 = o2 ? u0 : v0;
        int z1 = o2 ? u1 : v1;
        int z2 = o2 ? v2 : u2;
        int z3 = o2 ? v3 : u3;
        int P = pixBase + wvn * 64 + j * 16 + (lane & 12);
        int n = P / 784, rem = P - n * 784;
        size_t addr = (size_t)n * 200704 + (size_t)c * 784 + rem;
        float4 xr = *(const float4*)(xres + addr);
        float4 y;
        y.x = fmaxf((float)z0 * sc + tc + xr.x, 0.f);
        y.y = fmaxf((float)z1 * sc + tc + xr.y, 0.f);
        y.z = fmaxf((float)z2 * sc + tc + xr.z, 0.f);
        y.w = fmaxf((float)z3 * sc + tc + xr.w, 0.f);
        *(float4*)(fout + addr) = y;
      }
    }
  }
}

extern "C" void kernel_launch(void* const* d_in, const int* in_sizes, int n_in,
                              void* d_out, int out_size, void* d_ws, size_t ws_size,
                              hipStream_t stream) {
  const float* x  = (const float*)d_in[0];
  const float* w1 = (const float*)d_in[1];
  const float* g1 = (const float*)d_in[2];
  const float* b1 = (const float*)d_in[3];
  const float* m1 = (const float*)d_in[4];
  const float* v1 = (const float*)d_in[5];
  const float* w2 = (const float*)d_in[6];
  const float* g2 = (const float*)d_in[7];
  const float* b2 = (const float*)d_in[8];
  const float* m2 = (const float*)d_in[9];
  const float* v2 = (const float*)d_in[10];

  char* ws = (char*)d_ws;
  float* partial = (float*)ws;
  float* s1 = (float*)(ws + 1024);
  float* t1 = (float*)(ws + 2048);
  float* s2 = (float*)(ws + 3072);
  float* t2 = (float*)(ws + 4096);
  unsigned char* a1 = (unsigned char*)(ws + 8192);
  unsigned char* a2 = a1 + ABUF;
  signed char* wq1 = (signed char*)(a2 + ABUF);
  signed char* wq2 = wq1 + 589824;

  void (*k0)(const unsigned char*, const signed char*, const float*, const float*,
             const float*, unsigned char*, float*) = conv_gemm<0>;
  void (*k1)(const unsigned char*, const signed char*, const float*, const float*,
             const float*, unsigned char*, float*) = conv_gemm<1>;
  hipFuncSetAttribute((const void*)k0, hipFuncAttributeMaxDynamicSharedMemorySize, 131072);
  hipFuncSetAttribute((const void*)k1, hipFuncAttributeMaxDynamicSharedMemorySize, 131072);

  pre_k<<<384, 256, 0, stream>>>(x, a1, a2, w1, w2, partial,
                                 g1, b1, m1, v1, g2, b2, m2, v2, s1, t1, s2, t2);
  wquant_k<<<dim3(256, 2), 256, 0, stream>>>(w1, w2, partial, wq1, wq2);
  conv_gemm<0><<<196, 512, 131072, stream>>>(a1, wq1, s1, t1, nullptr, a2, nullptr);
  conv_gemm<1><<<196, 512, 131072, stream>>>(a2, wq2, s2, t2, x, nullptr, (float*)d_out);
}